// Round 9
// baseline (596.758 us; speedup 1.0000x reference)
//
#include <hip/hip_runtime.h>
#include <math.h>
#include <stdint.h>

#define NN 30000
#define EE 480000
#define MPAD 30080    // 235 * 128
#define NPAD 30720    // histogram entries (>= NN, 120 KB LDS, mult of 1024)
#define NB_HIST 32    // privatized-histogram blocks
#define CHUNK 15000   // EE / NB_HIST

typedef __attribute__((ext_vector_type(8))) short short8;
typedef __attribute__((ext_vector_type(4))) float floatx4;

// ---------------- bf16 helpers ----------------
__device__ __forceinline__ float b2f(ushort u) {
    union { uint u; float f; } c; c.u = ((uint)u) << 16; return c.f;
}
__device__ __forceinline__ ushort f2b(float f) {
    union { float f; uint u; } c; c.f = f;
    uint u = c.u;
    uint r = (u + 0x7FFFu + ((u >> 16) & 1u)) >> 16;
    return (ushort)r;
}
// fast softplus: max(x,0) + ln2 * log2(1 + 2^(-|x|*log2e))
__device__ __forceinline__ float softplus_f(float x) {
    float a = fabsf(x) * 1.44269504f;
    float t = __builtin_amdgcn_exp2f(-a);
    float l = __builtin_amdgcn_logf(1.f + t);
    return fmaxf(x, 0.f) + 0.69314718f * l;
}

// ---- async global->LDS, 16B per lane. LDS dest = wave-uniform base + lane*16.
__device__ __forceinline__ void gld_lds16(const void* g, void* lds) {
    __builtin_amdgcn_global_load_lds(
        (__attribute__((address_space(1))) void*)(uintptr_t)(g),
        (__attribute__((address_space(3))) void*)(uint32_t)(uintptr_t)(lds),
        16, 0, 0);
}

// ---- raw barrier + fine-grained vmcnt (pipeline primitives) ----
__device__ __forceinline__ void barrier_raw() {
    __asm__ volatile("s_barrier" ::: "memory");
}
template <int N>
__device__ __forceinline__ void waitcnt_vm() {
    if constexpr (N == 0) __asm__ volatile("s_waitcnt vmcnt(0)" ::: "memory");
    else if constexpr (N == 2) __asm__ volatile("s_waitcnt vmcnt(2)" ::: "memory");
    else if constexpr (N == 3) __asm__ volatile("s_waitcnt vmcnt(3)" ::: "memory");
    else if constexpr (N == 4) __asm__ volatile("s_waitcnt vmcnt(4)" ::: "memory");
    else if constexpr (N == 8) __asm__ volatile("s_waitcnt vmcnt(8)" ::: "memory");
}

// ============================================================================
// R15: preprocessing de-atomic'd via private LDS histograms + counting sort.
// R18: totals are the signal (+-20% per-dispatch noise); gemm_bk64 = best.
// R20/R21 (measured): deep-prefetch pipelines (4-buf vmcnt(12)) land at the
// same ~50us as 1-deep -- source-level pipelining can't break the 2-barrier
// structure's ceiling (guide m131-m140 precedent). GEMM structure is PARKED.
// R21: SpMV2 of a layer needs ALL Tx1, but each GEMM block needs Tx2 only on
// its OWN 128 rows -> fuse SpMV2 as a GEMM prologue (gather own stripe, write
// to A+2fi, vmcnt(0)+barrier, run the UNCHANGED loop; stripe re-read is
// L2-hot). Applied to L4 (no redundancy) and L5 (2x, same-XCD-absorbed);
// L6 keeps standalone SpMV2 (4x redundant gather > boundary saving).
// ============================================================================

// ---- fused pre-pass 1: LDS histograms (col counts + row deg) + x->bf16 +
// weight conv. Hist blocks first (long pole, 32 CUs); dense blocks grid-
// strided x8 to stay fat at the 1-block/CU occupancy the 120 KB LDS forces.
__global__ __launch_bounds__(256) void pre1_fused(
        const int* __restrict__ row, const int* __restrict__ col,
        const float* __restrict__ ew,
        int* __restrict__ Hpart, float* __restrict__ Dpart,
        const float* __restrict__ x, ushort* __restrict__ xb,
        const float* __restrict__ W1, const float* __restrict__ W2,
        const float* __restrict__ W3, const float* __restrict__ W4,
        const float* __restrict__ W5, const float* __restrict__ W6,
        ushort* __restrict__ B1, ushort* __restrict__ B2,
        ushort* __restrict__ B3, ushort* __restrict__ B4,
        ushort* __restrict__ B5, ushort* __restrict__ B6) {
    __shared__ int hist[NPAD];               // 120 KB
    int b = blockIdx.x;
    int t = threadIdx.x;
    if (b < NB_HIST) {
        int e0 = b * CHUNK, e1 = e0 + CHUNK; // 32*15000 == EE exactly
        // ---- pass A: col counts ----
        #pragma unroll
        for (int i = 0; i < NPAD / 1024; ++i)
            *(int4*)(&hist[(i * 256 + t) * 4]) = make_int4(0, 0, 0, 0);
        __syncthreads();
        int e = e0 + t;
        for (; e + 2048 <= e1; e += 2048) {
            int c0 = col[e],        c1 = col[e + 256];
            int c2 = col[e + 512],  c3 = col[e + 768];
            int c4 = col[e + 1024], c5 = col[e + 1280];
            int c6 = col[e + 1536], c7 = col[e + 1792];
            atomicAdd(&hist[c0], 1); atomicAdd(&hist[c1], 1);
            atomicAdd(&hist[c2], 1); atomicAdd(&hist[c3], 1);
            atomicAdd(&hist[c4], 1); atomicAdd(&hist[c5], 1);
            atomicAdd(&hist[c6], 1); atomicAdd(&hist[c7], 1);
        }
        for (; e < e1; e += 256) atomicAdd(&hist[col[e]], 1);
        __syncthreads();
        #pragma unroll
        for (int i = 0; i < NPAD / 1024; ++i)
            *(int4*)(&Hpart[(size_t)b * NPAD + (i * 256 + t) * 4]) =
                *(const int4*)(&hist[(i * 256 + t) * 4]);
        __syncthreads();
        // ---- pass B: deg (float) ----
        float* histf = (float*)hist;
        #pragma unroll
        for (int i = 0; i < NPAD / 1024; ++i)
            *(float4*)(&histf[(i * 256 + t) * 4]) = make_float4(0.f, 0.f, 0.f, 0.f);
        __syncthreads();
        e = e0 + t;
        for (; e + 1024 <= e1; e += 1024) {
            int r0 = row[e],       r1 = row[e + 256];
            int r2 = row[e + 512], r3 = row[e + 768];
            float w0 = ew[e],       w1 = ew[e + 256];
            float w2 = ew[e + 512], w3 = ew[e + 768];
            atomicAdd(&histf[r0], w0); atomicAdd(&histf[r1], w1);
            atomicAdd(&histf[r2], w2); atomicAdd(&histf[r3], w3);
        }
        for (; e < e1; e += 256) atomicAdd(&histf[row[e]], ew[e]);
        __syncthreads();
        #pragma unroll
        for (int i = 0; i < NPAD / 1024; ++i)
            *(float4*)(&Dpart[(size_t)b * NPAD + (i * 256 + t) * 4]) =
                *(const float4*)(&histf[(i * 256 + t) * 4]);
    } else if (b < NB_HIST + 480) {
        int id = b - NB_HIST;                // copy_x: 960000 float4s
        #pragma unroll
        for (int i = 0; i < 8; ++i) {
            int idx = id * 2048 + i * 256 + t;
            if (idx < NN * 128 / 4) {
                float4 v = *(const float4*)(x + (size_t)idx * 4);
                ushort4 o;
                o.x = f2b(v.x); o.y = f2b(v.y); o.z = f2b(v.z); o.w = f2b(v.w);
                *(ushort4*)(xb + (size_t)idx * 4) = o;
            }
        }
    } else {
        int id = b - NB_HIST - 480;          // wconv: 530432 elems
        #pragma unroll
        for (int i = 0; i < 8; ++i) {
            int idx = id * 2048 + i * 256 + t;
            if (idx < 6144) {                       // L1: 48*128
                int r = idx >> 7, k = idx & 127;
                int j = r >> 4, n = r & 15;
                B1[idx] = f2b(W1[(j * 128 + k) * 16 + n]);
            } else if (idx < 8192) {                // L2: 32*64, K=48
                int tt = idx - 6144; int n = tt >> 6, k = tt & 63;
                B2[tt] = f2b(k < 48 ? W2[k * 32 + n] : 0.f);
            } else if (idx < 14336) {               // L3: 64*96
                int tt = idx - 8192; int n = tt / 96, k = tt - n * 96;
                B3[tt] = f2b(W3[k * 64 + n]);
            } else if (idx < 38912) {               // L4: 128*192
                int tt = idx - 14336; int n = tt / 192, k = tt - n * 192;
                B4[tt] = f2b(W4[k * 128 + n]);
            } else if (idx < 137216) {              // L5: 256*384
                int tt = idx - 38912; int n = tt / 384, k = tt - n * 384;
                B5[tt] = f2b(W5[k * 256 + n]);
            } else if (idx < 530432) {              // L6: 512*768
                int tt = idx - 137216; int n = tt / 768, k = tt - n * 768;
                B6[tt] = f2b(W6[k * 512 + n]);
            }
        }
    }
}

// ---- column reduce: counts[c] = sum_b H[b][c]; H[b][c] <- exclusive prefix
// over blocks (counting-sort base); deg[c] = sum_b D[b][c]. All coalesced.
__global__ __launch_bounds__(256) void col_reduce(
        int* __restrict__ Hpart, const float* __restrict__ Dpart,
        int* __restrict__ counts, float* __restrict__ deg) {
    int c = blockIdx.x * 256 + threadIdx.x;   // grid 120 -> 30720 exact
    int run = 0;
    #pragma unroll
    for (int b = 0; b < NB_HIST; ++b) {
        int v = Hpart[(size_t)b * NPAD + c];
        Hpart[(size_t)b * NPAD + c] = run;
        run += v;
    }
    counts[c] = run;
    float s = 0.f;
    #pragma unroll
    for (int b = 0; b < NB_HIST; ++b) s += Dpart[(size_t)b * NPAD + c];
    deg[c] = s;
}

// ---- single-block exclusive scan over counts -> offs ----------------------
__global__ __launch_bounds__(1024) void scan_one(
        const int* __restrict__ counts, int* __restrict__ offs) {
    __shared__ int ws[16];
    int t = threadIdx.x;
    int wave = t >> 6, lane = t & 63;
    int base = t * 32;
    int c[32];
    int s = 0;
    if (base < NN) {
        #pragma unroll
        for (int g = 0; g < 8; ++g) {
            int4 v = *(const int4*)(counts + base + g * 4);
            c[g * 4 + 0] = v.x; c[g * 4 + 1] = v.y;
            c[g * 4 + 2] = v.z; c[g * 4 + 3] = v.w;
        }
        #pragma unroll
        for (int i = 0; i < 32; ++i) s += c[i];
    } else {
        #pragma unroll
        for (int i = 0; i < 32; ++i) c[i] = 0;
    }
    int incl = s;
    #pragma unroll
    for (int off = 1; off < 64; off <<= 1) {
        int xv = __shfl_up(incl, off);
        if (lane >= off) incl += xv;
    }
    if (lane == 63) ws[wave] = incl;
    __syncthreads();
    if (wave == 0) {
        int v = (lane < 16) ? ws[lane] : 0;
        #pragma unroll
        for (int off = 1; off < 16; off <<= 1) {
            int xv = __shfl_up(v, off);
            if (lane >= off) v += xv;
        }
        if (lane < 16) ws[lane] = v;         // inclusive wave sums
    }
    __syncthreads();
    int wbase = (wave == 0) ? 0 : ws[wave - 1];
    int run = wbase + incl - s;              // exclusive prefix for this thread
    if (base < NN) {
        int o[32];
        #pragma unroll
        for (int i = 0; i < 32; ++i) { o[i] = run; run += c[i]; }
        #pragma unroll
        for (int g = 0; g < 8; ++g) {
            int4 v = make_int4(o[g * 4], o[g * 4 + 1], o[g * 4 + 2], o[g * 4 + 3]);
            *(int4*)(offs + base + g * 4) = v;
        }
    }
    if (t == 0) offs[NN] = EE;
}

// ---------------- MFMA GEMM body, BN<=64 path, BK=32, double-buffered ------
template <int BN, bool ACT>
__device__ __forceinline__ void gemm_mfma_body(
        int bid, const ushort* __restrict__ A, int lda, int K,
        const ushort* __restrict__ Bt, const float* __restrict__ bias,
        ushort* __restrict__ Out, int ldo) {
    constexpr int BM = 128, BK = 32;
    constexpr int SM = 32;                    // 4 waves along M
    constexpr int FM = 2;
    constexpr int FN = BN / 16;
    constexpr int CB = BN / 16;               // B staging calls (1KB each)
    constexpr int WAITN = (BN == 64) ? 3 : 2; // per-wave loads/stage (min)
    __shared__ __align__(16) ushort As[2][BM][BK];
    __shared__ __align__(16) ushort Bs[2][BN][BK];
    int tid = threadIdx.x;
    int wv = tid >> 6, ln = tid & 63;
    int q = ln >> 4, r16 = ln & 15;
    int m0 = bid * BM;

    int lrow = ln >> 2;
    int gseg = (ln & 3) ^ ((ln >> 3) & 3);
    const ushort* Abase = A + (size_t)(m0 + lrow) * lda + gseg * 8;
    const ushort* Bbase = Bt + (size_t)lrow * K + gseg * 8;

    floatx4 acc[FM][FN];
    #pragma unroll
    for (int i = 0; i < FM; ++i)
        #pragma unroll
        for (int j = 0; j < FN; ++j) acc[i][j] = (floatx4){0.f, 0.f, 0.f, 0.f};

    int sw = (q ^ ((r16 >> 1) & 3)) * 8;
    int aoff[FM], boff[FN];
    #pragma unroll
    for (int i = 0; i < FM; ++i) aoff[i] = (wv * SM + i * 16 + r16) * BK + sw;
    #pragma unroll
    for (int j = 0; j < FN; ++j) boff[j] = (j * 16 + r16) * BK + sw;

    auto stage = [&](int b, int k0) {
        gld_lds16(Abase + (size_t)(wv * 16) * lda + k0, &As[b][wv * 16][0]);
        gld_lds16(Abase + (size_t)(64 + wv * 16) * lda + k0, &As[b][64 + wv * 16][0]);
        if constexpr (CB == 4) {
            gld_lds16(Bbase + (size_t)(wv * 16) * K + k0, &Bs[b][wv * 16][0]);
        } else {
            if (wv < CB) gld_lds16(Bbase + (size_t)(wv * 16) * K + k0, &Bs[b][wv * 16][0]);
        }
    };
    auto compute = [&](int b) {
        const ushort* ldsA = &As[b][0][0];
        const ushort* ldsB = &Bs[b][0][0];
        short8 af[FM], bf[FN];
        #pragma unroll
        for (int i = 0; i < FM; ++i) af[i] = *(const short8*)(ldsA + aoff[i]);
        #pragma unroll
        for (int j = 0; j < FN; ++j) bf[j] = *(const short8*)(ldsB + boff[j]);
        #pragma unroll
        for (int i = 0; i < FM; ++i)
            #pragma unroll
            for (int j = 0; j < FN; ++j)
                acc[i][j] = __builtin_amdgcn_mfma_f32_16x16x32_bf16(
                    af[i], bf[j], acc[i][j], 0, 0, 0);
    };

    int nIter = K / BK;
    stage(0, 0);
    for (int i = 0; i < nIter; ++i) {
        int cur = i & 1;
        barrier_raw();                    // all waves done reading buf cur^1
        if (i + 1 < nIter) {
            stage(cur ^ 1, (i + 1) * BK); // prefetch next tile
            waitcnt_vm<WAITN>();          // own tile-i loads landed
        } else {
            waitcnt_vm<0>();
        }
        barrier_raw();                    // tile i complete in LDS
        compute(cur);
    }
    #pragma unroll
    for (int i = 0; i < FM; ++i) {
        #pragma unroll
        for (int j = 0; j < FN; ++j) {
            int n = j * 16 + r16;
            float bv = ACT ? bias[n] : 0.f;
            #pragma unroll
            for (int r = 0; r < 4; ++r) {
                int m = m0 + wv * SM + i * 16 + q * 4 + r;
                float v = acc[i][j][r] + bv;
                Out[(size_t)m * ldo + n] = f2b(ACT ? softplus_f(v) : v);
            }
        }
    }
}

template <int BN, bool ACT = true>
__global__ __launch_bounds__(256) void gemm_mfma(
        const ushort* __restrict__ A, int lda, int K,
        const ushort* __restrict__ Bt,
        const float* __restrict__ bias,
        ushort* __restrict__ Out, int ldo) {
    gemm_mfma_body<BN, ACT>(blockIdx.x, A, lda, K, Bt, bias, Out, ldo);
}

// ---- fused pre-pass 2: counting-sort scatter (LDS cursors seeded from
// offs + per-block prefix; ZERO global atomics) + L1 GEMM (Y = xb @ Bt1).
__global__ __launch_bounds__(256) void pre2_fused(
        const int* __restrict__ row, const int* __restrict__ col,
        const float* __restrict__ ew, const float* __restrict__ deg,
        const int* __restrict__ offs, const int* __restrict__ Hpart,
        int2* __restrict__ csr_rw,
        const ushort* __restrict__ xb, const ushort* __restrict__ Bt1,
        ushort* __restrict__ Ybuf) {
    int b = blockIdx.x;
    if (b < NB_HIST) {
        __shared__ int cur[NPAD];            // 120 KB cursors
        int t = threadIdx.x;
        #pragma unroll
        for (int i = 0; i < NPAD / 1024; ++i) {
            int idx = (i * 256 + t) * 4;
            int4 o = *(const int4*)(offs + idx);
            int4 pfx = *(const int4*)(Hpart + (size_t)b * NPAD + idx);
            cur[idx + 0] = o.x + pfx.x;
            cur[idx + 1] = o.y + pfx.y;
            cur[idx + 2] = o.z + pfx.z;
            cur[idx + 3] = o.w + pfx.w;
        }
        __syncthreads();
        int e0 = b * CHUNK, e1 = e0 + CHUNK;
        int e = e0 + t;
        for (; e + 1024 <= e1; e += 1024) {
            int r0 = row[e],       r1 = row[e + 256];
            int r2 = row[e + 512], r3 = row[e + 768];
            int c0 = col[e],       c1 = col[e + 256];
            int c2 = col[e + 512], c3 = col[e + 768];
            float w0 = ew[e],       w1 = ew[e + 256];
            float w2 = ew[e + 512], w3 = ew[e + 768];
            float d0 = deg[r0], d1 = deg[r1], d2 = deg[r2], d3 = deg[r3];
            float v0 = (d0 > 0.f) ? (-w0 / d0) : 0.f;
            float v1 = (d1 > 0.f) ? (-w1 / d1) : 0.f;
            float v2 = (d2 > 0.f) ? (-w2 / d2) : 0.f;
            float v3 = (d3 > 0.f) ? (-w3 / d3) : 0.f;
            int p0 = atomicAdd(&cur[c0], 1);
            int p1 = atomicAdd(&cur[c1], 1);
            int p2 = atomicAdd(&cur[c2], 1);
            int p3 = atomicAdd(&cur[c3], 1);
            csr_rw[p0] = make_int2(r0, __float_as_int(v0));
            csr_rw[p1] = make_int2(r1, __float_as_int(v1));
            csr_rw[p2] = make_int2(r2, __float_as_int(v2));
            csr_rw[p3] = make_int2(r3, __float_as_int(v3));
        }
        for (; e < e1; e += 256) {
            int r = row[e];
            float d = deg[r];
            float wv = (d > 0.f) ? (-ew[e] / d) : 0.f;
            int pos = atomicAdd(&cur[col[e]], 1);
            csr_rw[pos] = make_int2(r, __float_as_int(wv));
        }
    } else {
        gemm_mfma_body<48, false>(b - NB_HIST, xb, 128, 128, Bt1, nullptr,
                                  Ybuf, 48);
    }
}

// ---------------- SpMV gather, small FI (16/32): node-packed waves ---------
template <int FI>
__global__ __launch_bounds__(256) void lmv_bf16(
        const ushort* __restrict__ A, ushort* __restrict__ Out,
        const ushort* __restrict__ Sub, int ldi, int ldo,
        const int* __restrict__ offs, const int2* __restrict__ rw,
        float scale, int N) {
    constexpr int NPW = 64 / FI;
    int wave = threadIdx.x >> 6;
    int lane = threadIdx.x & 63;
    int sub = lane / FI;
    int fbase = lane & (FI - 1);
    int node = blockIdx.x * (4 * NPW) + wave * NPW + sub;
    if (node >= N) return;
    int e0 = offs[node], e1 = offs[node + 1];
    float acc[4];
    #pragma unroll
    for (int c = 0; c < 4; ++c) acc[c] = 0.f;
    int e = e0;
    for (; e + 4 <= e1; e += 4) {
        int2 u0 = rw[e], u1 = rw[e + 1], u2 = rw[e + 2], u3 = rw[e + 3];
        acc[0] += __int_as_float(u0.y) * b2f(A[(size_t)u0.x * ldi + fbase]);
        acc[1] += __int_as_float(u1.y) * b2f(A[(size_t)u1.x * ldi + fbase]);
        acc[2] += __int_as_float(u2.y) * b2f(A[(size_t)u2.x * ldi + fbase]);
        acc[3] += __int_as_float(u3.y) * b2f(A[(size_t)u3.x * ldi + fbase]);
    }
    for (; e < e1; ++e) {
        int2 u = rw[e];
        acc[0] += __int_as_float(u.y) * b2f(A[(size_t)u.x * ldi + fbase]);
    }
    float a = (acc[0] + acc[1]) + (acc[2] + acc[3]);
    ushort* o = Out + (size_t)node * ldo + fbase;
    if (Sub) {
        const ushort* s = Sub + (size_t)node * ldo + fbase;
        *o = f2b(scale * a - b2f(*s));
    } else {
        *o = f2b(scale * a);
    }
}

// ---- L1 tail fused: z3 = Lhat@Z2 (16-wide), h1 = softplus(Y0+Z1+2z3-Y2+b) --
__global__ __launch_bounds__(256) void lmv_l1_final(
        const ushort* __restrict__ Z,    // (N,32) = [Z1|Z2]
        const ushort* __restrict__ Y,    // (N,48) = [Y0|Y1|Y2]
        const float* __restrict__ b,     // b1[16]
        ushort* __restrict__ Out,        // (N,64), cols [0,16)
        const int* __restrict__ offs, const int2* __restrict__ rw, int N) {
    int wave = threadIdx.x >> 6;
    int lane = threadIdx.x & 63;
    int sub = lane >> 4, f = lane & 15;
    int node = blockIdx.x * 16 + wave * 4 + sub;
    if (node >= N) return;
    int e0 = offs[node], e1 = offs[node + 1];
    const ushort* Z2 = Z + 16;
    float acc[4];
    #pragma unroll
    for (int c = 0; c < 4; ++c) acc[c] = 0.f;
    int e = e0;
    for (; e + 4 <= e1; e += 4) {
        int2 u0 = rw[e], u1 = rw[e + 1], u2 = rw[e + 2], u3 = rw[e + 3];
        acc[0] += __int_as_float(u0.y) * b2f(Z2[(size_t)u0.x * 32 + f]);
        acc[1] += __int_as_float(u1.y) * b2f(Z2[(size_t)u1.x * 32 + f]);
        acc[2] += __int_as_float(u2.y) * b2f(Z2[(size_t)u2.x * 32 + f]);
        acc[3] += __int_as_float(u3.y) * b2f(Z2[(size_t)u3.x * 32 + f]);
    }
    for (; e < e1; ++e) {
        int2 u = rw[e];
        acc[0] += __int_as_float(u.y) * b2f(Z2[(size_t)u.x * 32 + f]);
    }
    float z3 = (acc[0] + acc[1]) + (acc[2] + acc[3]);
    float y0 = b2f(Y[(size_t)node * 48 + f]);
    float y2 = b2f(Y[(size_t)node * 48 + 32 + f]);
    float z1 = b2f(Z[(size_t)node * 32 + f]);
    float v = y0 + z1 + 2.f * z3 - y2 + b[f];
    Out[(size_t)node * 64 + f] = f2b(softplus_f(v));
}

// ---------------- SpMV gather, edge-group (fi = LPG*4) ---------------------
// Wave = 1 node; 64/LPG groups of LPG lanes each own a DIFFERENT edge; every
// lane loads ushort4 (8 B). Butterfly shfl_xor over group bits reduces.
template <int LPG>   // lanes per group: 16 -> fi=64, 32 -> fi=128
__global__ __launch_bounds__(256) void lmv_grp(
        const ushort* __restrict__ A, ushort* __restrict__ Out,
        const ushort* __restrict__ Sub, int ld,
        const int* __restrict__ offs, const int2* __restrict__ rw,
        float scale) {
    constexpr int EG = 64 / LPG;        // concurrent edges per wave
    int node = blockIdx.x * 4 + (threadIdx.x >> 6);   // NN % 4 == 0
    int lane = threadIdx.x & 63;
    int g = lane / LPG;
    int li = lane % LPG;
    int fbase = li * 4;
    int e0 = __builtin_amdgcn_readfirstlane(offs[node]);
    int e1 = __builtin_amdgcn_readfirstlane(offs[node + 1]);
    float a0[4], a1[4];
    #pragma unroll
    for (int j = 0; j < 4; ++j) { a0[j] = 0.f; a1[j] = 0.f; }
    int e = e0 + g;
    for (; e + EG < e1; e += 2 * EG) {     // 2 chains, 2*EG edges in flight
        int2 u0 = rw[e];
        int2 u1 = rw[e + EG];
        float w0 = __int_as_float(u0.y), w1 = __int_as_float(u1.y);
        ushort4 v0 = *(const ushort4*)(A + (size_t)u0.x * ld + fbase);
        ushort4 v1 = *(const ushort4*)(A + (size_t)u1.x * ld + fbase);
        a0[0] += w0 * b2f(v0.x); a0[1] += w0 * b2f(v0.y);
        a0[2] += w0 * b2f(v0.z); a0[3] += w0 * b2f(v0.w);
        a1[0] += w1 * b2f(v1.x); a1[1] += w1 * b2f(v1.y);
        a1[2] += w1 * b2f(v1.z); a1[3] += w1 * b2f(v1.w);
    }
    if (e < e1) {                           // at most one leftover per group
        int2 u = rw[e];
        float w = __int_as_float(u.y);
        ushort4 v = *(const ushort4*)(A + (size_t)u.x * ld + fbase);
        a0[0] += w * b2f(v.x); a0[1] += w * b2f(v.y);
        a0[2] += w * b2f(v.z); a0[3] += w * b2f(v.w);
    }
    #pragma unroll
    for (int j = 0; j < 4; ++j) {
        float a = a0[j] + a1[j];
        #pragma unroll
        for (int off = LPG; off < 64; off <<= 1)
            a += __shfl_xor(a, off);        // sum across groups (same li set)
        a0[j] = a;
    }
    if (g == 0) {
        ushort* o = Out + (size_t)node * ld + fbase;
        ushort4 w;
        if (Sub) {
            ushort4 s = *(const ushort4*)(Sub + (size_t)node * ld + fbase);
            w.x = f2b(scale * a0[0] - b2f(s.x));
            w.y = f2b(scale * a0[1] - b2f(s.y));
            w.z = f2b(scale * a0[2] - b2f(s.z));
            w.w = f2b(scale * a0[3] - b2f(s.w));
        } else {
            w.x = f2b(scale * a0[0]); w.y = f2b(scale * a0[1]);
            w.z = f2b(scale * a0[2]); w.w = f2b(scale * a0[3]);
        }
        *(ushort4*)o = w;
    }
}

// ---------------- SpMV gather, vectorized (fi=256), scalar CSR -------------
// One wave per node; lane reads 4 contiguous bf16 -> one 512B VMEM per edge.
// CSR via readfirstlane; CH=8 accumulator chains (CH=16 spilled -- R12).
template <int VEC>
__global__ __launch_bounds__(256) void lmv_vec(
        const ushort* __restrict__ A, ushort* __restrict__ Out,
        const ushort* __restrict__ Sub, int ld,
        const int* __restrict__ offs, const int2* __restrict__ rw,
        float scale) {
    constexpr int CH = 8;
    int node = blockIdx.x * 4 + (threadIdx.x >> 6);   // NN % 4 == 0, no guard
    int lane = threadIdx.x & 63;
    int fbase = lane * VEC;
    int e0 = __builtin_amdgcn_readfirstlane(offs[node]);
    int e1 = __builtin_amdgcn_readfirstlane(offs[node + 1]);
    float acc[CH][VEC];
    #pragma unroll
    for (int c = 0; c < CH; ++c)
        #pragma unroll
        for (int v = 0; v < VEC; ++v) acc[c][v] = 0.f;
    int e = e0;
    for (; e + CH <= e1; e += CH) {
        #pragma unroll
        for (int c = 0; c < CH; ++c) {
            int2 u = rw[e + c];             // scalar (uniform) 8B load
            int r = u.x;
            float we = __int_as_float(u.y);
            const ushort* pr = A + (size_t)r * ld + fbase;
            if constexpr (VEC == 4) {
                ushort4 uu = *(const ushort4*)pr;
                acc[c][0] += we * b2f(uu.x); acc[c][1] += we * b2f(uu.y);
                acc[c][2] += we * b2f(uu.z); acc[c][3] += we * b2f(uu.w);
            } else if constexpr (VEC == 2) {
                ushort2 uu = *(const ushort2*)pr;
                acc[c][0] += we * b2f(uu.x); acc[c][1] += we * b2f(uu.y);
            } else {
                acc[c][0] += we * b2f(*pr);
            }
        }
    }
    for (; e < e1; ++e) {
        int c = e & (CH - 1);
        int2 u = rw[e];
        int r = u.x;
        float we = __int_as_float(u.y);
        const ushort* pr = A + (size_t)r * ld + fbase;
        if constexpr (VEC == 4) {
            ushort4 uu = *(const ushort4*)pr;
            acc[c][0] += we * b2f(uu.x); acc[c][1] += we * b2f(uu.y);
            acc[c][2] += we * b2f(uu.z); acc[c][3] += we * b2f(uu.w);
        } else if constexpr (VEC == 2) {
            ushort2 uu = *(const ushort2*)pr;
            acc[c][0] += we * b2f(uu.x); acc[c][1] += we * b2f(uu.y);
        } else {
            acc[c][0] += we * b2f(*pr);
        }
    }
    #pragma unroll
    for (int c = 1; c < CH; ++c)
        #pragma unroll
        for (int v = 0; v < VEC; ++v) acc[0][v] += acc[c][v];
    ushort* o = Out + (size_t)node * ld + fbase;
    if (Sub) {
        const ushort* s = Sub + (size_t)node * ld + fbase;
        ushort tmp[VEC];
        #pragma unroll
        for (int v = 0; v < VEC; ++v) tmp[v] = f2b(scale * acc[0][v] - b2f(s[v]));
        #pragma unroll
        for (int v = 0; v < VEC; ++v) o[v] = tmp[v];
    } else {
        #pragma unroll
        for (int v = 0; v < VEC; ++v) o[v] = f2b(scale * acc[0][v]);
    }
}

// ---------------- MFMA GEMM, BN=128 path, BK=64 + double-buffered LDS ------
// R18: best-total configuration restored. 8 gld_lds16/wave/stage; vmcnt(8).
// R13: bijective XCD swizzle (m204) keeps the (1<<YB) yb-sharers of one A
// panel on one XCD L2.
// R21: FUSE_FI > 0 -> SpMV2 fused as prologue: each block computes the Tx2
// stripe for its OWN 128 M-rows (gather from global Tx1 = A+FUSE_FI, rows
// from csr), writes it to A+2*FUSE_FI, then vmcnt(0)+barrier and runs the
// UNCHANGED K-loop (stripe re-read is same-block L2-hot). Pad rows (>= NN)
// skipped (offs is garbage there; GEMM poison on pad rows is harmless, as
// established). yb-redundant blocks write identical bytes (race-free).
template <bool FC, int YB, int FUSE_FI>
__global__ __launch_bounds__(256) void gemm_bk64(
        const ushort* __restrict__ A, int lda, int K,
        const ushort* __restrict__ Bt,
        const float* __restrict__ bias,
        ushort* __restrict__ Out, int ldo,
        const float* __restrict__ fcw, float* __restrict__ fcout,
        const int* __restrict__ offs, const int2* __restrict__ rw) {
    constexpr int BM = 128, BN = 128, BK = 64;
    __shared__ __align__(16) ushort As[2][BM][BK];   // 2 x 16 KB
    __shared__ __align__(16) ushort Bs[2][BN][BK];   // 2 x 16 KB
    int tid = threadIdx.x;
    int wv = tid >> 6, ln = tid & 63;
    int wm = wv & 1, wn = wv >> 1;
    int q = ln >> 4, r16 = ln & 15;
    int nwg = gridDim.x;
    int orig = blockIdx.x;
    int xcd = orig & 7;
    int qq = nwg >> 3, rr = nwg & 7;
    int wbase = (xcd < rr) ? xcd * (qq + 1) : rr * (qq + 1) + (xcd - rr) * qq;
    int wgid = wbase + (orig >> 3);
    int yb = wgid & ((1 << YB) - 1);
    int xb = wgid >> YB;
    int m0 = xb * BM;
    int n0 = yb * BN;

    // ---- R21 fused SpMV2 prologue ----
    if constexpr (FUSE_FI > 0) {
        constexpr int LPG = FUSE_FI / 4;     // lanes per edge-group
        constexpr int EG = 64 / LPG;         // concurrent edges per wave
        int g = ln / LPG, li = ln % LPG;
        int fb = li * 4;
        const ushort* T1 = A + FUSE_FI;
        const ushort* T0 = A;
        ushort* T2 = const_cast<ushort*>(A) + 2 * FUSE_FI;
        for (int rr2 = 0; rr2 < 32; ++rr2) {
            int node = m0 + wv * 32 + rr2;
            if (node < NN) {
                int e0 = __builtin_amdgcn_readfirstlane(offs[node]);
                int e1 = __builtin_amdgcn_readfirstlane(offs[node + 1]);
                float a0[4], a1[4];
                #pragma unroll
                for (int j = 0; j < 4; ++j) { a0[j] = 0.f; a1[j] = 0.f; }
                int e = e0 + g;
                for (; e + EG < e1; e += 2 * EG) {   // 2 chains in flight
                    int2 u0 = rw[e];
                    int2 u1 = rw[e + EG];
                    float w0 = __int_as_float(u0.y), w1 = __int_as_float(u1.y);
                    ushort4 v0 = *(const ushort4*)(T1 + (size_t)u0.x * lda + fb);
                    ushort4 v1 = *(const ushort4*)(T1 + (size_t)u1.x * lda + fb);
                    a0[0] += w0 * b2f(v0.x); a0[1] += w0 * b2f(v0.y);
                    a0[2] += w0 * b2f(v0.z); a0[3] += w0 * b2f(v0.w);
                    a1[0] += w1 * b2f(v1.x); a1[1] += w1 * b2f(v1.y);
                    a1[2] += w1 * b2f(v1.z); a1[3] += w1 * b2f(v1.w);
                }
                if (e < e1) {
                    int2 u = rw[e];
                    float w = __int_as_float(u.y);
                    ushort4 v = *(const ushort4*)(T1 + (size_t)u.x * lda + fb);
                    a0[0] += w * b2f(v.x); a0[1] += w * b2f(v.y);
                    a0[2] += w * b2f(v.z); a0[3] += w * b2f(v.w);
                }
                #pragma unroll
                for (int j = 0; j < 4; ++j) {
                    float a = a0[j] + a1[j];
                    #pragma unroll
                    for (int off = LPG; off < 64; off <<= 1)
                        a += __shfl_xor(a, off);
                    a0[j] = a;
                }
                if (g == 0) {
                    ushort4 s = *(const ushort4*)(T0 + (size_t)node * lda + fb);
                    ushort4 o;
                    o.x = f2b(2.f * a0[0] - b2f(s.x));
                    o.y = f2b(2.f * a0[1] - b2f(s.y));
                    o.z = f2b(2.f * a0[2] - b2f(s.z));
                    o.w = f2b(2.f * a0[3] - b2f(s.w));
                    *(ushort4*)(T2 + (size_t)node * lda + fb) = o;
                }
            }
        }
        waitcnt_vm<0>();      // stripe stores committed (L2)
        barrier_raw();        // all waves' stripes written before any staging
    }

    int lrow8 = ln >> 3, slds = ln & 7;
    int gseg = slds ^ lrow8;
    const ushort* Abase = A + (size_t)(m0 + lrow8) * lda + gseg * 8;
    const ushort* Bbase = Bt + (size_t)(n0 + lrow8) * K + gseg * 8;

    floatx4 acc[4][4];
    #pragma unroll
    for (int i = 0; i < 4; ++i)
        #pragma unroll
        for (int j = 0; j < 4; ++j) acc[i][j] = (floatx4){0.f, 0.f, 0.f, 0.f};

    int r7 = r16 & 7;
    int aoff[2][4], boff[2][4];
    #pragma unroll
    for (int s = 0; s < 2; ++s) {
        int segp = ((s * 4 + q) ^ r7) * 8;
        #pragma unroll
        for (int i = 0; i < 4; ++i) {
            aoff[s][i] = (wm * 64 + i * 16 + r16) * BK + segp;
            boff[s][i] = (wn * 64 + i * 16 + r16) * BK + segp;
        }
    }

    auto stage = [&](int b, int k0) {
        #pragma unroll
        for (int g = 0; g < 4; ++g)
            gld_lds16(Abase + (size_t)(wv * 8 + g * 32) * lda + k0,
                      &As[b][wv * 8 + g * 32][0]);
        #pragma unroll
        for (int g = 0; g < 4; ++g)
            gld_lds16(Bbase + (size_t)(wv * 8 + g * 32) * K + k0,
                      &Bs[b][wv * 8 + g * 32][0]);
    };
    auto compute = [&](int b) {
        const ushort* ldsA = &As[b][0][0];
        const ushort* ldsB = &Bs[b][0][0];
        #pragma unroll
        for (int s = 0; s < 2; ++s) {
            short8 af[4], bf[4];
            #pragma unroll
            for (int i = 0; i < 4; ++i) af[i] = *(const short8*)(ldsA + aoff[s][i]);
            #pragma unroll
            for (int j = 0; j < 4; ++j) bf[j] = *(const short8*)(ldsB + boff[s][j]);
            #pragma unroll
            for (int i = 0; i < 4; ++i)
                #pragma unroll
                for (int j = 0; j < 4; ++j)
                    acc[i][j] = __builtin_amdgcn_mfma_f32_16x16x32_bf16(
                        af[i], bf[j], acc[i][j], 0, 0, 0);
        }
    };

    int nIter = K / BK;
    stage(0, 0);
    for (int i = 0; i < nIter; ++i) {
        int cur = i & 1;
        barrier_raw();                    // all waves done reading buf cur^1
        if (i + 1 < nIter) {
            stage(cur ^ 1, (i + 1) * BK);
            waitcnt_vm<8>();              // own tile-i loads landed
        } else {
            waitcnt_vm<0>();
        }
        barrier_raw();                    // tile i complete in LDS
        compute(cur);
    }

    if constexpr (FC) {
        int pb = yb * 2 + wn;   // per-(yb,wn) partial slot — no shared dst
        #pragma unroll
        for (int i = 0; i < 4; ++i) {
            #pragma unroll
            for (int r = 0; r < 4; ++r) {
                float p0 = 0.f, p1 = 0.f, p2 = 0.f;
                #pragma unroll
                for (int j = 0; j < 4; ++j) {
                    int n = n0 + wn * 64 + j * 16 + r16;
                    float v = softplus_f(acc[i][j][r] + bias[n]);
                    p0 += v * fcw[n * 3 + 0];
                    p1 += v * fcw[n * 3 + 1];
                    p2 += v * fcw[n * 3 + 2];
                }
                #pragma unroll
                for (int off = 1; off < 16; off <<= 1) {
                    p0 += __shfl_xor(p0, off);
                    p1 += __shfl_xor(p1, off);
                    p2 += __shfl_xor(p2, off);
                }
                if (r16 == 0) {
                    int m = m0 + wm * 64 + i * 16 + q * 4 + r;
                    float* dst = fcout + ((size_t)pb * MPAD + m) * 3;
                    dst[0] = p0; dst[1] = p1; dst[2] = p2;
                }
            }
        }
    } else {
        #pragma unroll
        for (int i = 0; i < 4; ++i) {
            #pragma unroll
            for (int j = 0; j < 4; ++j) {
                int n = n0 + wn * 64 + j * 16 + r16;
                float bv = bias[n];
                #pragma unroll
                for (int r = 0; r < 4; ++r) {
                    int m = m0 + wm * 64 + i * 16 + q * 4 + r;
                    Out[(size_t)m * ldo + n] = f2b(softplus_f(acc[i][j][r] + bv));
                }
            }
        }
    }
}

// ---------------- FC partial reduce: out = sum of 8 partials + fcb ---------
__global__ __launch_bounds__(256) void fc_reduce(
        const float* __restrict__ part, const float* __restrict__ fcb,
        float* __restrict__ out) {
    int idx = blockIdx.x * blockDim.x + threadIdx.x;
    if (idx >= NN * 3) return;
    int c = idx - (idx / 3) * 3;
    float s = 0.f;
    #pragma unroll
    for (int pb = 0; pb < 8; ++pb)
        s += part[(size_t)pb * MPAD * 3 + idx];
    out[idx] = s + fcb[c];
}

static inline size_t align256(size_t x) { return (x + 255) & ~(size_t)255; }

extern "C" void kernel_launch(void* const* d_in, const int* in_sizes, int n_in,
                              void* d_out, int out_size, void* d_ws, size_t ws_size,
                              hipStream_t stream) {
    const float* x   = (const float*)d_in[0];
    const int*   ei  = (const int*)d_in[1];
    const float* ew  = (const float*)d_in[2];
    const float* W[6]  = { (const float*)d_in[4],  (const float*)d_in[6],
                           (const float*)d_in[8],  (const float*)d_in[10],
                           (const float*)d_in[12], (const float*)d_in[14] };
    const float* Bv[6] = { (const float*)d_in[5],  (const float*)d_in[7],
                           (const float*)d_in[9],  (const float*)d_in[11],
                           (const float*)d_in[13], (const float*)d_in[15] };
    const float* fc_w = (const float*)d_in[16];
    const float* fc_b = (const float*)d_in[17];
    float* out = (float*)d_out;

    const int* e_row = ei;        // edge_index[0]
    const int* e_col = ei + EE;   // edge_index[1]

    // layers 2..6 (index 1..5)
    const int fi_arr[5]   = { 16, 32, 64, 128, 256 };
    const int fo_arr[5]   = { 32, 64, 128, 256, 512 };
    const int Kpad_arr[5] = { 64, 96, 192, 384, 768 };
    const int ldo_arr[5]  = { 96, 192, 384, 768, 512 };

    // ---- workspace carve ----
    char* p = (char*)d_ws;
    float* deg    = (float*)p; p += align256((size_t)NPAD * 4);
    int*   counts = (int*)p;   p += align256((size_t)NPAD * 4);
    int*   offs   = (int*)p;   p += align256((size_t)(NPAD + 4) * 4);
    int*   Hpart  = (int*)p;   p += align256((size_t)NB_HIST * NPAD * 4);
    float* Dpart  = (float*)p; p += align256((size_t)NB_HIST * NPAD * 4);
    int2*  csr_rw = (int2*)p;  p += align256((size_t)EE * 8);
    ushort* Bt1   = (ushort*)p; p += align256((size_t)48 * 128 * 2);
    ushort* Bt[5];
    for (int L = 0; L < 5; ++L) {
        Bt[L] = (ushort*)p;
        p += align256((size_t)fo_arr[L] * Kpad_arr[L] * 2);
    }
    float* fcpart = (float*)p; p += align256((size_t)8 * MPAD * 3 * 4);
    ushort* xb   = (ushort*)p; p += align256((size_t)MPAD * 128 * 2);
    ushort* Ybuf = (ushort*)p; p += align256((size_t)MPAD * 48 * 2);
    ushort* Zbuf = (ushort*)p; p += align256((size_t)MPAD * 32 * 2);
    ushort* buf0 = (ushort*)p; p += align256((size_t)MPAD * 768 * 2);
    ushort* buf1 = (ushort*)p; p += align256((size_t)MPAD * 768 * 2);
    (void)ws_size; (void)n_in; (void)in_sizes; (void)out_size;

    // No memsets needed: deg/counts fully written by col_reduce; H/D fully
    // written by pre1's flush; csr fully written by the counting-sort scatter.

    // ---- fused pre-pass 1: LDS histograms + x->bf16 + weight conv ----
    pre1_fused<<<NB_HIST + 480 + 260, 256, 0, stream>>>(
        e_row, e_col, ew, Hpart, Dpart, x, xb,
        W[0], W[1], W[2], W[3], W[4], W[5],
        Bt1, Bt[0], Bt[1], Bt[2], Bt[3], Bt[4]);

    // ---- column reduce + per-block prefix + deg ----
    col_reduce<<<NPAD / 256, 256, 0, stream>>>(Hpart, Dpart, counts, deg);

    // ---- single-block scan: counts -> offs ----
    scan_one<<<1, 1024, 0, stream>>>(counts, offs);

    // ---- fused pre-pass 2: counting-sort scatter + L1 GEMM ----
    pre2_fused<<<NB_HIST + MPAD / 128, 256, 0, stream>>>(
        e_row, e_col, ew, deg, offs, Hpart, csr_rw, xb, Bt1, Ybuf);

    // Z = Lhat @ [Y1|Y2]  (32-wide)
    lmv_bf16<32><<<(NN + 7) / 8, 256, 0, stream>>>(
        Ybuf + 16, Zbuf, nullptr, 48, 32, offs, csr_rw, 1.0f, NN);
    // fused: z3 = Lhat@Z2 ; h1 = softplus(Y0+Z1+2z3-Y2+b1) -> buf1 [0,16), ld 64
    lmv_l1_final<<<(NN + 15) / 16, 256, 0, stream>>>(
        Zbuf, Ybuf, Bv[0], buf1, offs, csr_rw, NN);

    // ---- Layers 2..6 ----
    ushort* Abuf[5] = { buf1, buf0, buf1, buf0, buf1 };
    ushort* Obuf[5] = { buf0, buf1, buf0, buf1, buf0 };

    for (int L = 0; L < 5; ++L) {
        int fi = fi_arr[L];
        int ldA = Kpad_arr[L];
        int ldO = ldo_arr[L];
        ushort* A = Abuf[L];
        ushort* O = Obuf[L];

        // SpMV pass 1 (Tx1 = Lhat@Tx0). Pass 2 is fused into the GEMM for
        // L4/L5 (R21); standalone for the other layers.
        switch (fi) {
            case 16:
                lmv_bf16<16><<<(NN + 15) / 16, 256, 0, stream>>>(
                    A, A + fi, nullptr, ldA, ldA, offs, csr_rw, 1.0f, NN);
                lmv_bf16<16><<<(NN + 15) / 16, 256, 0, stream>>>(
                    A + fi, A + 2 * fi, A, ldA, ldA, offs, csr_rw, 2.0f, NN);
                break;
            case 32:
                lmv_bf16<32><<<(NN + 7) / 8, 256, 0, stream>>>(
                    A, A + fi, nullptr, ldA, ldA, offs, csr_rw, 1.0f, NN);
                lmv_bf16<32><<<(NN + 7) / 8, 256, 0, stream>>>(
                    A + fi, A + 2 * fi, A, ldA, ldA, offs, csr_rw, 2.0f, NN);
                break;
            case 64:    // L4: pass 1 only; pass 2 fused into GEMM prologue
                lmv_grp<16><<<NN / 4, 256, 0, stream>>>(
                    A, A + fi, nullptr, ldA, offs, csr_rw, 1.0f);
                break;
            case 128:   // L5: pass 1 only; pass 2 fused into GEMM prologue
                lmv_grp<32><<<NN / 4, 256, 0, stream>>>(
                    A, A + fi, nullptr, ldA, offs, csr_rw, 1.0f);
                break;
            default:    // L6 (fi=256): both passes standalone
                lmv_vec<4><<<NN / 4, 256, 0, stream>>>(
                    A, A + fi, nullptr, ldA, offs, csr_rw, 1.0f);
                lmv_vec<4><<<NN / 4, 256, 0, stream>>>(
                    A + fi, A + 2 * fi, A, ldA, offs, csr_rw, 2.0f);
                break;
        }

        int K = Kpad_arr[L];
        switch (fo_arr[L]) {
            case 32:
                gemm_mfma<32><<<dim3(MPAD / 128), 256, 0, stream>>>(
                    A, ldA, K, Bt[L], Bv[L + 1], O, ldO);
                break;
            case 64:
                gemm_mfma<64><<<dim3(MPAD / 128), 256, 0, stream>>>(
                    A, ldA, K, Bt[L], Bv[L + 1], O, ldO);
                break;
            case 128:   // L4: K=192, fused SpMV2 (fi=64) + BK=64 DB GEMM
                gemm_bk64<false, 0, 64><<<dim3(MPAD / 128), 256, 0, stream>>>(
                    A, ldA, K, Bt[L], Bv[L + 1], O, ldO, nullptr, nullptr,
                    offs, csr_rw);
                break;
            case 256:   // L5: K=384, fused SpMV2 (fi=128), y-inner
                gemm_bk64<false, 1, 128><<<dim3(MPAD / 128 * 2), 256, 0, stream>>>(
                    A, ldA, K, Bt[L], Bv[L + 1], O, ldO, nullptr, nullptr,
                    offs, csr_rw);
                break;
            default:    // L6: K=768, fused FC -> 8 partial buffers
                gemm_bk64<true, 2, 0><<<dim3(MPAD / 128 * 4), 256, 0, stream>>>(
                    A, ldA, K, Bt[L], Bv[L + 1], nullptr, 0, fc_w, fcpart,
                    offs, csr_rw);
                break;
        }
    }

    // ---- final: out = sum of 8 FC partials + fc_b ----
    fc_reduce<<<(NN * 3 + 255) / 256, 256, 0, stream>>>(fcpart, fc_b, out);
}

// Round 10
// 459.369 us; speedup vs baseline: 1.2991x; 1.2991x over previous
//
#include <hip/hip_runtime.h>
#include <math.h>
#include <stdint.h>

#define NN 30000
#define EE 480000
#define MPAD 30080    // 235 * 128
#define NPAD 30720    // histogram entries (>= NN, 120 KB LDS, mult of 1024)
#define NB_HIST 32    // privatized-histogram blocks
#define CHUNK 15000   // EE / NB_HIST

typedef __attribute__((ext_vector_type(8))) short short8;
typedef __attribute__((ext_vector_type(4))) float floatx4;

// ---------------- bf16 helpers ----------------
__device__ __forceinline__ float b2f(ushort u) {
    union { uint u; float f; } c; c.u = ((uint)u) << 16; return c.f;
}
__device__ __forceinline__ ushort f2b(float f) {
    union { float f; uint u; } c; c.f = f;
    uint u = c.u;
    uint r = (u + 0x7FFFu + ((u >> 16) & 1u)) >> 16;
    return (ushort)r;
}
// fast softplus: max(x,0) + ln2 * log2(1 + 2^(-|x|*log2e))
__device__ __forceinline__ float softplus_f(float x) {
    float a = fabsf(x) * 1.44269504f;
    float t = __builtin_amdgcn_exp2f(-a);
    float l = __builtin_amdgcn_logf(1.f + t);
    return fmaxf(x, 0.f) + 0.69314718f * l;
}

// ---- async global->LDS, 16B per lane. LDS dest = wave-uniform base + lane*16.
__device__ __forceinline__ void gld_lds16(const void* g, void* lds) {
    __builtin_amdgcn_global_load_lds(
        (__attribute__((address_space(1))) void*)(uintptr_t)(g),
        (__attribute__((address_space(3))) void*)(uint32_t)(uintptr_t)(lds),
        16, 0, 0);
}

// ---- raw barrier + fine-grained vmcnt (pipeline primitives) ----
__device__ __forceinline__ void barrier_raw() {
    __asm__ volatile("s_barrier" ::: "memory");
}
template <int N>
__device__ __forceinline__ void waitcnt_vm() {
    if constexpr (N == 0) __asm__ volatile("s_waitcnt vmcnt(0)" ::: "memory");
    else if constexpr (N == 2) __asm__ volatile("s_waitcnt vmcnt(2)" ::: "memory");
    else if constexpr (N == 3) __asm__ volatile("s_waitcnt vmcnt(3)" ::: "memory");
    else if constexpr (N == 4) __asm__ volatile("s_waitcnt vmcnt(4)" ::: "memory");
    else if constexpr (N == 8) __asm__ volatile("s_waitcnt vmcnt(8)" ::: "memory");
}

// ============================================================================
// R15: preprocessing de-atomic'd via private LDS histograms + counting sort.
// R18: totals are the signal (+-20% per-dispatch noise); this configuration
// (gemm_bk64 + lmv_grp/lmv_vec) measured 459.7/460.5 -- the session best.
// FAILED RESTRUCTURES (all measured, all reverted):
//   R16 BK=32 128sq GEMM: 469.1 (latency regime unchanged)
//   R17 BN=64 N-split: 464.8 (occupancy doubled, MfmaUtil flat -> not TLP)
//   R19 XCD-pinned chunked SpMV: 632.0 (b%8->XCD pinning does not hold;
//       FETCH 54MB = no-caching bound)
//   R20 4-buf vmcnt(12) pipeline: 464.6 (same ~50us as 1-deep; source-level
//       pipelining can't break the 2-barrier ceiling, guide m131-m140)
//   R21 SpMV2 fused as GEMM prologue: 596.8 (fusion strangled the gather's
//       parallelism: 235-block grid vs SpMV's 7500 waves; 125us/dispatch)
// Remaining gap = GEMM barrier-drain ceiling + L3-latency-bound random
// gather at irreducible bytes + dispatch boundaries.
// ============================================================================

// ---- fused pre-pass 1: LDS histograms (col counts + row deg) + x->bf16 +
// weight conv. Hist blocks first (long pole, 32 CUs); dense blocks grid-
// strided x8 to stay fat at the 1-block/CU occupancy the 120 KB LDS forces.
__global__ __launch_bounds__(256) void pre1_fused(
        const int* __restrict__ row, const int* __restrict__ col,
        const float* __restrict__ ew,
        int* __restrict__ Hpart, float* __restrict__ Dpart,
        const float* __restrict__ x, ushort* __restrict__ xb,
        const float* __restrict__ W1, const float* __restrict__ W2,
        const float* __restrict__ W3, const float* __restrict__ W4,
        const float* __restrict__ W5, const float* __restrict__ W6,
        ushort* __restrict__ B1, ushort* __restrict__ B2,
        ushort* __restrict__ B3, ushort* __restrict__ B4,
        ushort* __restrict__ B5, ushort* __restrict__ B6) {
    __shared__ int hist[NPAD];               // 120 KB
    int b = blockIdx.x;
    int t = threadIdx.x;
    if (b < NB_HIST) {
        int e0 = b * CHUNK, e1 = e0 + CHUNK; // 32*15000 == EE exactly
        // ---- pass A: col counts ----
        #pragma unroll
        for (int i = 0; i < NPAD / 1024; ++i)
            *(int4*)(&hist[(i * 256 + t) * 4]) = make_int4(0, 0, 0, 0);
        __syncthreads();
        int e = e0 + t;
        for (; e + 2048 <= e1; e += 2048) {
            int c0 = col[e],        c1 = col[e + 256];
            int c2 = col[e + 512],  c3 = col[e + 768];
            int c4 = col[e + 1024], c5 = col[e + 1280];
            int c6 = col[e + 1536], c7 = col[e + 1792];
            atomicAdd(&hist[c0], 1); atomicAdd(&hist[c1], 1);
            atomicAdd(&hist[c2], 1); atomicAdd(&hist[c3], 1);
            atomicAdd(&hist[c4], 1); atomicAdd(&hist[c5], 1);
            atomicAdd(&hist[c6], 1); atomicAdd(&hist[c7], 1);
        }
        for (; e < e1; e += 256) atomicAdd(&hist[col[e]], 1);
        __syncthreads();
        #pragma unroll
        for (int i = 0; i < NPAD / 1024; ++i)
            *(int4*)(&Hpart[(size_t)b * NPAD + (i * 256 + t) * 4]) =
                *(const int4*)(&hist[(i * 256 + t) * 4]);
        __syncthreads();
        // ---- pass B: deg (float) ----
        float* histf = (float*)hist;
        #pragma unroll
        for (int i = 0; i < NPAD / 1024; ++i)
            *(float4*)(&histf[(i * 256 + t) * 4]) = make_float4(0.f, 0.f, 0.f, 0.f);
        __syncthreads();
        e = e0 + t;
        for (; e + 1024 <= e1; e += 1024) {
            int r0 = row[e],       r1 = row[e + 256];
            int r2 = row[e + 512], r3 = row[e + 768];
            float w0 = ew[e],       w1 = ew[e + 256];
            float w2 = ew[e + 512], w3 = ew[e + 768];
            atomicAdd(&histf[r0], w0); atomicAdd(&histf[r1], w1);
            atomicAdd(&histf[r2], w2); atomicAdd(&histf[r3], w3);
        }
        for (; e < e1; e += 256) atomicAdd(&histf[row[e]], ew[e]);
        __syncthreads();
        #pragma unroll
        for (int i = 0; i < NPAD / 1024; ++i)
            *(float4*)(&Dpart[(size_t)b * NPAD + (i * 256 + t) * 4]) =
                *(const float4*)(&histf[(i * 256 + t) * 4]);
    } else if (b < NB_HIST + 480) {
        int id = b - NB_HIST;                // copy_x: 960000 float4s
        #pragma unroll
        for (int i = 0; i < 8; ++i) {
            int idx = id * 2048 + i * 256 + t;
            if (idx < NN * 128 / 4) {
                float4 v = *(const float4*)(x + (size_t)idx * 4);
                ushort4 o;
                o.x = f2b(v.x); o.y = f2b(v.y); o.z = f2b(v.z); o.w = f2b(v.w);
                *(ushort4*)(xb + (size_t)idx * 4) = o;
            }
        }
    } else {
        int id = b - NB_HIST - 480;          // wconv: 530432 elems
        #pragma unroll
        for (int i = 0; i < 8; ++i) {
            int idx = id * 2048 + i * 256 + t;
            if (idx < 6144) {                       // L1: 48*128
                int r = idx >> 7, k = idx & 127;
                int j = r >> 4, n = r & 15;
                B1[idx] = f2b(W1[(j * 128 + k) * 16 + n]);
            } else if (idx < 8192) {                // L2: 32*64, K=48
                int tt = idx - 6144; int n = tt >> 6, k = tt & 63;
                B2[tt] = f2b(k < 48 ? W2[k * 32 + n] : 0.f);
            } else if (idx < 14336) {               // L3: 64*96
                int tt = idx - 8192; int n = tt / 96, k = tt - n * 96;
                B3[tt] = f2b(W3[k * 64 + n]);
            } else if (idx < 38912) {               // L4: 128*192
                int tt = idx - 14336; int n = tt / 192, k = tt - n * 192;
                B4[tt] = f2b(W4[k * 128 + n]);
            } else if (idx < 137216) {              // L5: 256*384
                int tt = idx - 38912; int n = tt / 384, k = tt - n * 384;
                B5[tt] = f2b(W5[k * 256 + n]);
            } else if (idx < 530432) {              // L6: 512*768
                int tt = idx - 137216; int n = tt / 768, k = tt - n * 768;
                B6[tt] = f2b(W6[k * 512 + n]);
            }
        }
    }
}

// ---- column reduce: counts[c] = sum_b H[b][c]; H[b][c] <- exclusive prefix
// over blocks (counting-sort base); deg[c] = sum_b D[b][c]. All coalesced.
__global__ __launch_bounds__(256) void col_reduce(
        int* __restrict__ Hpart, const float* __restrict__ Dpart,
        int* __restrict__ counts, float* __restrict__ deg) {
    int c = blockIdx.x * 256 + threadIdx.x;   // grid 120 -> 30720 exact
    int run = 0;
    #pragma unroll
    for (int b = 0; b < NB_HIST; ++b) {
        int v = Hpart[(size_t)b * NPAD + c];
        Hpart[(size_t)b * NPAD + c] = run;
        run += v;
    }
    counts[c] = run;
    float s = 0.f;
    #pragma unroll
    for (int b = 0; b < NB_HIST; ++b) s += Dpart[(size_t)b * NPAD + c];
    deg[c] = s;
}

// ---- single-block exclusive scan over counts -> offs ----------------------
__global__ __launch_bounds__(1024) void scan_one(
        const int* __restrict__ counts, int* __restrict__ offs) {
    __shared__ int ws[16];
    int t = threadIdx.x;
    int wave = t >> 6, lane = t & 63;
    int base = t * 32;
    int c[32];
    int s = 0;
    if (base < NN) {
        #pragma unroll
        for (int g = 0; g < 8; ++g) {
            int4 v = *(const int4*)(counts + base + g * 4);
            c[g * 4 + 0] = v.x; c[g * 4 + 1] = v.y;
            c[g * 4 + 2] = v.z; c[g * 4 + 3] = v.w;
        }
        #pragma unroll
        for (int i = 0; i < 32; ++i) s += c[i];
    } else {
        #pragma unroll
        for (int i = 0; i < 32; ++i) c[i] = 0;
    }
    int incl = s;
    #pragma unroll
    for (int off = 1; off < 64; off <<= 1) {
        int xv = __shfl_up(incl, off);
        if (lane >= off) incl += xv;
    }
    if (lane == 63) ws[wave] = incl;
    __syncthreads();
    if (wave == 0) {
        int v = (lane < 16) ? ws[lane] : 0;
        #pragma unroll
        for (int off = 1; off < 16; off <<= 1) {
            int xv = __shfl_up(v, off);
            if (lane >= off) v += xv;
        }
        if (lane < 16) ws[lane] = v;         // inclusive wave sums
    }
    __syncthreads();
    int wbase = (wave == 0) ? 0 : ws[wave - 1];
    int run = wbase + incl - s;              // exclusive prefix for this thread
    if (base < NN) {
        int o[32];
        #pragma unroll
        for (int i = 0; i < 32; ++i) { o[i] = run; run += c[i]; }
        #pragma unroll
        for (int g = 0; g < 8; ++g) {
            int4 v = make_int4(o[g * 4], o[g * 4 + 1], o[g * 4 + 2], o[g * 4 + 3]);
            *(int4*)(offs + base + g * 4) = v;
        }
    }
    if (t == 0) offs[NN] = EE;
}

// ---------------- MFMA GEMM body, BN<=64 path, BK=32, double-buffered ------
template <int BN, bool ACT>
__device__ __forceinline__ void gemm_mfma_body(
        int bid, const ushort* __restrict__ A, int lda, int K,
        const ushort* __restrict__ Bt, const float* __restrict__ bias,
        ushort* __restrict__ Out, int ldo) {
    constexpr int BM = 128, BK = 32;
    constexpr int SM = 32;                    // 4 waves along M
    constexpr int FM = 2;
    constexpr int FN = BN / 16;
    constexpr int CB = BN / 16;               // B staging calls (1KB each)
    constexpr int WAITN = (BN == 64) ? 3 : 2; // per-wave loads/stage (min)
    __shared__ __align__(16) ushort As[2][BM][BK];
    __shared__ __align__(16) ushort Bs[2][BN][BK];
    int tid = threadIdx.x;
    int wv = tid >> 6, ln = tid & 63;
    int q = ln >> 4, r16 = ln & 15;
    int m0 = bid * BM;

    int lrow = ln >> 2;
    int gseg = (ln & 3) ^ ((ln >> 3) & 3);
    const ushort* Abase = A + (size_t)(m0 + lrow) * lda + gseg * 8;
    const ushort* Bbase = Bt + (size_t)lrow * K + gseg * 8;

    floatx4 acc[FM][FN];
    #pragma unroll
    for (int i = 0; i < FM; ++i)
        #pragma unroll
        for (int j = 0; j < FN; ++j) acc[i][j] = (floatx4){0.f, 0.f, 0.f, 0.f};

    int sw = (q ^ ((r16 >> 1) & 3)) * 8;
    int aoff[FM], boff[FN];
    #pragma unroll
    for (int i = 0; i < FM; ++i) aoff[i] = (wv * SM + i * 16 + r16) * BK + sw;
    #pragma unroll
    for (int j = 0; j < FN; ++j) boff[j] = (j * 16 + r16) * BK + sw;

    auto stage = [&](int b, int k0) {
        gld_lds16(Abase + (size_t)(wv * 16) * lda + k0, &As[b][wv * 16][0]);
        gld_lds16(Abase + (size_t)(64 + wv * 16) * lda + k0, &As[b][64 + wv * 16][0]);
        if constexpr (CB == 4) {
            gld_lds16(Bbase + (size_t)(wv * 16) * K + k0, &Bs[b][wv * 16][0]);
        } else {
            if (wv < CB) gld_lds16(Bbase + (size_t)(wv * 16) * K + k0, &Bs[b][wv * 16][0]);
        }
    };
    auto compute = [&](int b) {
        const ushort* ldsA = &As[b][0][0];
        const ushort* ldsB = &Bs[b][0][0];
        short8 af[FM], bf[FN];
        #pragma unroll
        for (int i = 0; i < FM; ++i) af[i] = *(const short8*)(ldsA + aoff[i]);
        #pragma unroll
        for (int j = 0; j < FN; ++j) bf[j] = *(const short8*)(ldsB + boff[j]);
        #pragma unroll
        for (int i = 0; i < FM; ++i)
            #pragma unroll
            for (int j = 0; j < FN; ++j)
                acc[i][j] = __builtin_amdgcn_mfma_f32_16x16x32_bf16(
                    af[i], bf[j], acc[i][j], 0, 0, 0);
    };

    int nIter = K / BK;
    stage(0, 0);
    for (int i = 0; i < nIter; ++i) {
        int cur = i & 1;
        barrier_raw();                    // all waves done reading buf cur^1
        if (i + 1 < nIter) {
            stage(cur ^ 1, (i + 1) * BK); // prefetch next tile
            waitcnt_vm<WAITN>();          // own tile-i loads landed
        } else {
            waitcnt_vm<0>();
        }
        barrier_raw();                    // tile i complete in LDS
        compute(cur);
    }
    #pragma unroll
    for (int i = 0; i < FM; ++i) {
        #pragma unroll
        for (int j = 0; j < FN; ++j) {
            int n = j * 16 + r16;
            float bv = ACT ? bias[n] : 0.f;
            #pragma unroll
            for (int r = 0; r < 4; ++r) {
                int m = m0 + wv * SM + i * 16 + q * 4 + r;
                float v = acc[i][j][r] + bv;
                Out[(size_t)m * ldo + n] = f2b(ACT ? softplus_f(v) : v);
            }
        }
    }
}

template <int BN, bool ACT = true>
__global__ __launch_bounds__(256) void gemm_mfma(
        const ushort* __restrict__ A, int lda, int K,
        const ushort* __restrict__ Bt,
        const float* __restrict__ bias,
        ushort* __restrict__ Out, int ldo) {
    gemm_mfma_body<BN, ACT>(blockIdx.x, A, lda, K, Bt, bias, Out, ldo);
}

// ---- fused pre-pass 2: counting-sort scatter (LDS cursors seeded from
// offs + per-block prefix; ZERO global atomics) + L1 GEMM (Y = xb @ Bt1).
__global__ __launch_bounds__(256) void pre2_fused(
        const int* __restrict__ row, const int* __restrict__ col,
        const float* __restrict__ ew, const float* __restrict__ deg,
        const int* __restrict__ offs, const int* __restrict__ Hpart,
        int2* __restrict__ csr_rw,
        const ushort* __restrict__ xb, const ushort* __restrict__ Bt1,
        ushort* __restrict__ Ybuf) {
    int b = blockIdx.x;
    if (b < NB_HIST) {
        __shared__ int cur[NPAD];            // 120 KB cursors
        int t = threadIdx.x;
        #pragma unroll
        for (int i = 0; i < NPAD / 1024; ++i) {
            int idx = (i * 256 + t) * 4;
            int4 o = *(const int4*)(offs + idx);
            int4 pfx = *(const int4*)(Hpart + (size_t)b * NPAD + idx);
            cur[idx + 0] = o.x + pfx.x;
            cur[idx + 1] = o.y + pfx.y;
            cur[idx + 2] = o.z + pfx.z;
            cur[idx + 3] = o.w + pfx.w;
        }
        __syncthreads();
        int e0 = b * CHUNK, e1 = e0 + CHUNK;
        int e = e0 + t;
        for (; e + 1024 <= e1; e += 1024) {
            int r0 = row[e],       r1 = row[e + 256];
            int r2 = row[e + 512], r3 = row[e + 768];
            int c0 = col[e],       c1 = col[e + 256];
            int c2 = col[e + 512], c3 = col[e + 768];
            float w0 = ew[e],       w1 = ew[e + 256];
            float w2 = ew[e + 512], w3 = ew[e + 768];
            float d0 = deg[r0], d1 = deg[r1], d2 = deg[r2], d3 = deg[r3];
            float v0 = (d0 > 0.f) ? (-w0 / d0) : 0.f;
            float v1 = (d1 > 0.f) ? (-w1 / d1) : 0.f;
            float v2 = (d2 > 0.f) ? (-w2 / d2) : 0.f;
            float v3 = (d3 > 0.f) ? (-w3 / d3) : 0.f;
            int p0 = atomicAdd(&cur[c0], 1);
            int p1 = atomicAdd(&cur[c1], 1);
            int p2 = atomicAdd(&cur[c2], 1);
            int p3 = atomicAdd(&cur[c3], 1);
            csr_rw[p0] = make_int2(r0, __float_as_int(v0));
            csr_rw[p1] = make_int2(r1, __float_as_int(v1));
            csr_rw[p2] = make_int2(r2, __float_as_int(v2));
            csr_rw[p3] = make_int2(r3, __float_as_int(v3));
        }
        for (; e < e1; e += 256) {
            int r = row[e];
            float d = deg[r];
            float wv = (d > 0.f) ? (-ew[e] / d) : 0.f;
            int pos = atomicAdd(&cur[col[e]], 1);
            csr_rw[pos] = make_int2(r, __float_as_int(wv));
        }
    } else {
        gemm_mfma_body<48, false>(b - NB_HIST, xb, 128, 128, Bt1, nullptr,
                                  Ybuf, 48);
    }
}

// ---------------- SpMV gather, small FI (16/32): node-packed waves ---------
template <int FI>
__global__ __launch_bounds__(256) void lmv_bf16(
        const ushort* __restrict__ A, ushort* __restrict__ Out,
        const ushort* __restrict__ Sub, int ldi, int ldo,
        const int* __restrict__ offs, const int2* __restrict__ rw,
        float scale, int N) {
    constexpr int NPW = 64 / FI;
    int wave = threadIdx.x >> 6;
    int lane = threadIdx.x & 63;
    int sub = lane / FI;
    int fbase = lane & (FI - 1);
    int node = blockIdx.x * (4 * NPW) + wave * NPW + sub;
    if (node >= N) return;
    int e0 = offs[node], e1 = offs[node + 1];
    float acc[4];
    #pragma unroll
    for (int c = 0; c < 4; ++c) acc[c] = 0.f;
    int e = e0;
    for (; e + 4 <= e1; e += 4) {
        int2 u0 = rw[e], u1 = rw[e + 1], u2 = rw[e + 2], u3 = rw[e + 3];
        acc[0] += __int_as_float(u0.y) * b2f(A[(size_t)u0.x * ldi + fbase]);
        acc[1] += __int_as_float(u1.y) * b2f(A[(size_t)u1.x * ldi + fbase]);
        acc[2] += __int_as_float(u2.y) * b2f(A[(size_t)u2.x * ldi + fbase]);
        acc[3] += __int_as_float(u3.y) * b2f(A[(size_t)u3.x * ldi + fbase]);
    }
    for (; e < e1; ++e) {
        int2 u = rw[e];
        acc[0] += __int_as_float(u.y) * b2f(A[(size_t)u.x * ldi + fbase]);
    }
    float a = (acc[0] + acc[1]) + (acc[2] + acc[3]);
    ushort* o = Out + (size_t)node * ldo + fbase;
    if (Sub) {
        const ushort* s = Sub + (size_t)node * ldo + fbase;
        *o = f2b(scale * a - b2f(*s));
    } else {
        *o = f2b(scale * a);
    }
}

// ---- L1 tail fused: z3 = Lhat@Z2 (16-wide), h1 = softplus(Y0+Z1+2z3-Y2+b) --
__global__ __launch_bounds__(256) void lmv_l1_final(
        const ushort* __restrict__ Z,    // (N,32) = [Z1|Z2]
        const ushort* __restrict__ Y,    // (N,48) = [Y0|Y1|Y2]
        const float* __restrict__ b,     // b1[16]
        ushort* __restrict__ Out,        // (N,64), cols [0,16)
        const int* __restrict__ offs, const int2* __restrict__ rw, int N) {
    int wave = threadIdx.x >> 6;
    int lane = threadIdx.x & 63;
    int sub = lane >> 4, f = lane & 15;
    int node = blockIdx.x * 16 + wave * 4 + sub;
    if (node >= N) return;
    int e0 = offs[node], e1 = offs[node + 1];
    const ushort* Z2 = Z + 16;
    float acc[4];
    #pragma unroll
    for (int c = 0; c < 4; ++c) acc[c] = 0.f;
    int e = e0;
    for (; e + 4 <= e1; e += 4) {
        int2 u0 = rw[e], u1 = rw[e + 1], u2 = rw[e + 2], u3 = rw[e + 3];
        acc[0] += __int_as_float(u0.y) * b2f(Z2[(size_t)u0.x * 32 + f]);
        acc[1] += __int_as_float(u1.y) * b2f(Z2[(size_t)u1.x * 32 + f]);
        acc[2] += __int_as_float(u2.y) * b2f(Z2[(size_t)u2.x * 32 + f]);
        acc[3] += __int_as_float(u3.y) * b2f(Z2[(size_t)u3.x * 32 + f]);
    }
    for (; e < e1; ++e) {
        int2 u = rw[e];
        acc[0] += __int_as_float(u.y) * b2f(Z2[(size_t)u.x * 32 + f]);
    }
    float z3 = (acc[0] + acc[1]) + (acc[2] + acc[3]);
    float y0 = b2f(Y[(size_t)node * 48 + f]);
    float y2 = b2f(Y[(size_t)node * 48 + 32 + f]);
    float z1 = b2f(Z[(size_t)node * 32 + f]);
    float v = y0 + z1 + 2.f * z3 - y2 + b[f];
    Out[(size_t)node * 64 + f] = f2b(softplus_f(v));
}

// ---------------- SpMV gather, edge-group (fi = LPG*4) ---------------------
// Wave = 1 node; 64/LPG groups of LPG lanes each own a DIFFERENT edge; every
// lane loads ushort4 (8 B). Butterfly shfl_xor over group bits reduces.
template <int LPG>   // lanes per group: 16 -> fi=64, 32 -> fi=128
__global__ __launch_bounds__(256) void lmv_grp(
        const ushort* __restrict__ A, ushort* __restrict__ Out,
        const ushort* __restrict__ Sub, int ld,
        const int* __restrict__ offs, const int2* __restrict__ rw,
        float scale) {
    constexpr int EG = 64 / LPG;        // concurrent edges per wave
    int node = blockIdx.x * 4 + (threadIdx.x >> 6);   // NN % 4 == 0
    int lane = threadIdx.x & 63;
    int g = lane / LPG;
    int li = lane % LPG;
    int fbase = li * 4;
    int e0 = __builtin_amdgcn_readfirstlane(offs[node]);
    int e1 = __builtin_amdgcn_readfirstlane(offs[node + 1]);
    float a0[4], a1[4];
    #pragma unroll
    for (int j = 0; j < 4; ++j) { a0[j] = 0.f; a1[j] = 0.f; }
    int e = e0 + g;
    for (; e + EG < e1; e += 2 * EG) {     // 2 chains, 2*EG edges in flight
        int2 u0 = rw[e];
        int2 u1 = rw[e + EG];
        float w0 = __int_as_float(u0.y), w1 = __int_as_float(u1.y);
        ushort4 v0 = *(const ushort4*)(A + (size_t)u0.x * ld + fbase);
        ushort4 v1 = *(const ushort4*)(A + (size_t)u1.x * ld + fbase);
        a0[0] += w0 * b2f(v0.x); a0[1] += w0 * b2f(v0.y);
        a0[2] += w0 * b2f(v0.z); a0[3] += w0 * b2f(v0.w);
        a1[0] += w1 * b2f(v1.x); a1[1] += w1 * b2f(v1.y);
        a1[2] += w1 * b2f(v1.z); a1[3] += w1 * b2f(v1.w);
    }
    if (e < e1) {                           // at most one leftover per group
        int2 u = rw[e];
        float w = __int_as_float(u.y);
        ushort4 v = *(const ushort4*)(A + (size_t)u.x * ld + fbase);
        a0[0] += w * b2f(v.x); a0[1] += w * b2f(v.y);
        a0[2] += w * b2f(v.z); a0[3] += w * b2f(v.w);
    }
    #pragma unroll
    for (int j = 0; j < 4; ++j) {
        float a = a0[j] + a1[j];
        #pragma unroll
        for (int off = LPG; off < 64; off <<= 1)
            a += __shfl_xor(a, off);        // sum across groups (same li set)
        a0[j] = a;
    }
    if (g == 0) {
        ushort* o = Out + (size_t)node * ld + fbase;
        ushort4 w;
        if (Sub) {
            ushort4 s = *(const ushort4*)(Sub + (size_t)node * ld + fbase);
            w.x = f2b(scale * a0[0] - b2f(s.x));
            w.y = f2b(scale * a0[1] - b2f(s.y));
            w.z = f2b(scale * a0[2] - b2f(s.z));
            w.w = f2b(scale * a0[3] - b2f(s.w));
        } else {
            w.x = f2b(scale * a0[0]); w.y = f2b(scale * a0[1]);
            w.z = f2b(scale * a0[2]); w.w = f2b(scale * a0[3]);
        }
        *(ushort4*)o = w;
    }
}

// ---------------- SpMV gather, vectorized (fi=256), scalar CSR -------------
// One wave per node; lane reads 4 contiguous bf16 -> one 512B VMEM per edge.
// CSR via readfirstlane; CH=8 accumulator chains (CH=16 spilled -- R12).
template <int VEC>
__global__ __launch_bounds__(256) void lmv_vec(
        const ushort* __restrict__ A, ushort* __restrict__ Out,
        const ushort* __restrict__ Sub, int ld,
        const int* __restrict__ offs, const int2* __restrict__ rw,
        float scale) {
    constexpr int CH = 8;
    int node = blockIdx.x * 4 + (threadIdx.x >> 6);   // NN % 4 == 0, no guard
    int lane = threadIdx.x & 63;
    int fbase = lane * VEC;
    int e0 = __builtin_amdgcn_readfirstlane(offs[node]);
    int e1 = __builtin_amdgcn_readfirstlane(offs[node + 1]);
    float acc[CH][VEC];
    #pragma unroll
    for (int c = 0; c < CH; ++c)
        #pragma unroll
        for (int v = 0; v < VEC; ++v) acc[c][v] = 0.f;
    int e = e0;
    for (; e + CH <= e1; e += CH) {
        #pragma unroll
        for (int c = 0; c < CH; ++c) {
            int2 u = rw[e + c];             // scalar (uniform) 8B load
            int r = u.x;
            float we = __int_as_float(u.y);
            const ushort* pr = A + (size_t)r * ld + fbase;
            if constexpr (VEC == 4) {
                ushort4 uu = *(const ushort4*)pr;
                acc[c][0] += we * b2f(uu.x); acc[c][1] += we * b2f(uu.y);
                acc[c][2] += we * b2f(uu.z); acc[c][3] += we * b2f(uu.w);
            } else if constexpr (VEC == 2) {
                ushort2 uu = *(const ushort2*)pr;
                acc[c][0] += we * b2f(uu.x); acc[c][1] += we * b2f(uu.y);
            } else {
                acc[c][0] += we * b2f(*pr);
            }
        }
    }
    for (; e < e1; ++e) {
        int c = e & (CH - 1);
        int2 u = rw[e];
        int r = u.x;
        float we = __int_as_float(u.y);
        const ushort* pr = A + (size_t)r * ld + fbase;
        if constexpr (VEC == 4) {
            ushort4 uu = *(const ushort4*)pr;
            acc[c][0] += we * b2f(uu.x); acc[c][1] += we * b2f(uu.y);
            acc[c][2] += we * b2f(uu.z); acc[c][3] += we * b2f(uu.w);
        } else if constexpr (VEC == 2) {
            ushort2 uu = *(const ushort2*)pr;
            acc[c][0] += we * b2f(uu.x); acc[c][1] += we * b2f(uu.y);
        } else {
            acc[c][0] += we * b2f(*pr);
        }
    }
    #pragma unroll
    for (int c = 1; c < CH; ++c)
        #pragma unroll
        for (int v = 0; v < VEC; ++v) acc[0][v] += acc[c][v];
    ushort* o = Out + (size_t)node * ld + fbase;
    if (Sub) {
        const ushort* s = Sub + (size_t)node * ld + fbase;
        ushort tmp[VEC];
        #pragma unroll
        for (int v = 0; v < VEC; ++v) tmp[v] = f2b(scale * acc[0][v] - b2f(s[v]));
        #pragma unroll
        for (int v = 0; v < VEC; ++v) o[v] = tmp[v];
    } else {
        #pragma unroll
        for (int v = 0; v < VEC; ++v) o[v] = f2b(scale * acc[0][v]);
    }
}

// ---------------- MFMA GEMM, BN=128 path, BK=64 + double-buffered LDS ------
// R18: best-total configuration. 8 gld_lds16 per wave per stage; vmcnt(8)
// keeps next tile in flight across the barrier.
// R13: bijective XCD swizzle (m204) keeps the (1<<YB) yb-sharers of one A
// panel on one XCD L2 (FETCH was 2x A without it).
template <bool FC = false, int YB = 0>
__global__ __launch_bounds__(256) void gemm_bk64(
        const ushort* __restrict__ A, int lda, int K,
        const ushort* __restrict__ Bt,
        const float* __restrict__ bias,
        ushort* __restrict__ Out, int ldo,
        const float* __restrict__ fcw, float* __restrict__ fcout) {
    constexpr int BM = 128, BN = 128, BK = 64;
    __shared__ __align__(16) ushort As[2][BM][BK];   // 2 x 16 KB
    __shared__ __align__(16) ushort Bs[2][BN][BK];   // 2 x 16 KB
    int tid = threadIdx.x;
    int wv = tid >> 6, ln = tid & 63;
    int wm = wv & 1, wn = wv >> 1;
    int q = ln >> 4, r16 = ln & 15;
    int nwg = gridDim.x;
    int orig = blockIdx.x;
    int xcd = orig & 7;
    int qq = nwg >> 3, rr = nwg & 7;
    int wbase = (xcd < rr) ? xcd * (qq + 1) : rr * (qq + 1) + (xcd - rr) * qq;
    int wgid = wbase + (orig >> 3);
    int yb = wgid & ((1 << YB) - 1);
    int xb = wgid >> YB;
    int m0 = xb * BM;
    int n0 = yb * BN;

    int lrow8 = ln >> 3, slds = ln & 7;
    int gseg = slds ^ lrow8;
    const ushort* Abase = A + (size_t)(m0 + lrow8) * lda + gseg * 8;
    const ushort* Bbase = Bt + (size_t)(n0 + lrow8) * K + gseg * 8;

    floatx4 acc[4][4];
    #pragma unroll
    for (int i = 0; i < 4; ++i)
        #pragma unroll
        for (int j = 0; j < 4; ++j) acc[i][j] = (floatx4){0.f, 0.f, 0.f, 0.f};

    int r7 = r16 & 7;
    int aoff[2][4], boff[2][4];
    #pragma unroll
    for (int s = 0; s < 2; ++s) {
        int segp = ((s * 4 + q) ^ r7) * 8;
        #pragma unroll
        for (int i = 0; i < 4; ++i) {
            aoff[s][i] = (wm * 64 + i * 16 + r16) * BK + segp;
            boff[s][i] = (wn * 64 + i * 16 + r16) * BK + segp;
        }
    }

    auto stage = [&](int b, int k0) {
        #pragma unroll
        for (int g = 0; g < 4; ++g)
            gld_lds16(Abase + (size_t)(wv * 8 + g * 32) * lda + k0,
                      &As[b][wv * 8 + g * 32][0]);
        #pragma unroll
        for (int g = 0; g < 4; ++g)
            gld_lds16(Bbase + (size_t)(wv * 8 + g * 32) * K + k0,
                      &Bs[b][wv * 8 + g * 32][0]);
    };
    auto compute = [&](int b) {
        const ushort* ldsA = &As[b][0][0];
        const ushort* ldsB = &Bs[b][0][0];
        #pragma unroll
        for (int s = 0; s < 2; ++s) {
            short8 af[4], bf[4];
            #pragma unroll
            for (int i = 0; i < 4; ++i) af[i] = *(const short8*)(ldsA + aoff[s][i]);
            #pragma unroll
            for (int j = 0; j < 4; ++j) bf[j] = *(const short8*)(ldsB + boff[s][j]);
            #pragma unroll
            for (int i = 0; i < 4; ++i)
                #pragma unroll
                for (int j = 0; j < 4; ++j)
                    acc[i][j] = __builtin_amdgcn_mfma_f32_16x16x32_bf16(
                        af[i], bf[j], acc[i][j], 0, 0, 0);
        }
    };

    int nIter = K / BK;
    stage(0, 0);
    for (int i = 0; i < nIter; ++i) {
        int cur = i & 1;
        barrier_raw();                    // all waves done reading buf cur^1
        if (i + 1 < nIter) {
            stage(cur ^ 1, (i + 1) * BK);
            waitcnt_vm<8>();              // own tile-i loads landed
        } else {
            waitcnt_vm<0>();
        }
        barrier_raw();                    // tile i complete in LDS
        compute(cur);
    }

    if constexpr (FC) {
        int pb = yb * 2 + wn;   // per-(yb,wn) partial slot — no shared dst
        #pragma unroll
        for (int i = 0; i < 4; ++i) {
            #pragma unroll
            for (int r = 0; r < 4; ++r) {
                float p0 = 0.f, p1 = 0.f, p2 = 0.f;
                #pragma unroll
                for (int j = 0; j < 4; ++j) {
                    int n = n0 + wn * 64 + j * 16 + r16;
                    float v = softplus_f(acc[i][j][r] + bias[n]);
                    p0 += v * fcw[n * 3 + 0];
                    p1 += v * fcw[n * 3 + 1];
                    p2 += v * fcw[n * 3 + 2];
                }
                #pragma unroll
                for (int off = 1; off < 16; off <<= 1) {
                    p0 += __shfl_xor(p0, off);
                    p1 += __shfl_xor(p1, off);
                    p2 += __shfl_xor(p2, off);
                }
                if (r16 == 0) {
                    int m = m0 + wm * 64 + i * 16 + q * 4 + r;
                    float* dst = fcout + ((size_t)pb * MPAD + m) * 3;
                    dst[0] = p0; dst[1] = p1; dst[2] = p2;
                }
            }
        }
    } else {
        #pragma unroll
        for (int i = 0; i < 4; ++i) {
            #pragma unroll
            for (int j = 0; j < 4; ++j) {
                int n = n0 + wn * 64 + j * 16 + r16;
                float bv = bias[n];
                #pragma unroll
                for (int r = 0; r < 4; ++r) {
                    int m = m0 + wm * 64 + i * 16 + q * 4 + r;
                    Out[(size_t)m * ldo + n] = f2b(softplus_f(acc[i][j][r] + bv));
                }
            }
        }
    }
}

// ---------------- FC partial reduce: out = sum of 8 partials + fcb ---------
__global__ __launch_bounds__(256) void fc_reduce(
        const float* __restrict__ part, const float* __restrict__ fcb,
        float* __restrict__ out) {
    int idx = blockIdx.x * blockDim.x + threadIdx.x;
    if (idx >= NN * 3) return;
    int c = idx - (idx / 3) * 3;
    float s = 0.f;
    #pragma unroll
    for (int pb = 0; pb < 8; ++pb)
        s += part[(size_t)pb * MPAD * 3 + idx];
    out[idx] = s + fcb[c];
}

static inline size_t align256(size_t x) { return (x + 255) & ~(size_t)255; }

extern "C" void kernel_launch(void* const* d_in, const int* in_sizes, int n_in,
                              void* d_out, int out_size, void* d_ws, size_t ws_size,
                              hipStream_t stream) {
    const float* x   = (const float*)d_in[0];
    const int*   ei  = (const int*)d_in[1];
    const float* ew  = (const float*)d_in[2];
    const float* W[6]  = { (const float*)d_in[4],  (const float*)d_in[6],
                           (const float*)d_in[8],  (const float*)d_in[10],
                           (const float*)d_in[12], (const float*)d_in[14] };
    const float* Bv[6] = { (const float*)d_in[5],  (const float*)d_in[7],
                           (const float*)d_in[9],  (const float*)d_in[11],
                           (const float*)d_in[13], (const float*)d_in[15] };
    const float* fc_w = (const float*)d_in[16];
    const float* fc_b = (const float*)d_in[17];
    float* out = (float*)d_out;

    const int* e_row = ei;        // edge_index[0]
    const int* e_col = ei + EE;   // edge_index[1]

    // layers 2..6 (index 1..5)
    const int fi_arr[5]   = { 16, 32, 64, 128, 256 };
    const int fo_arr[5]   = { 32, 64, 128, 256, 512 };
    const int Kpad_arr[5] = { 64, 96, 192, 384, 768 };
    const int ldo_arr[5]  = { 96, 192, 384, 768, 512 };

    // ---- workspace carve ----
    char* p = (char*)d_ws;
    float* deg    = (float*)p; p += align256((size_t)NPAD * 4);
    int*   counts = (int*)p;   p += align256((size_t)NPAD * 4);
    int*   offs   = (int*)p;   p += align256((size_t)(NPAD + 4) * 4);
    int*   Hpart  = (int*)p;   p += align256((size_t)NB_HIST * NPAD * 4);
    float* Dpart  = (float*)p; p += align256((size_t)NB_HIST * NPAD * 4);
    int2*  csr_rw = (int2*)p;  p += align256((size_t)EE * 8);
    ushort* Bt1   = (ushort*)p; p += align256((size_t)48 * 128 * 2);
    ushort* Bt[5];
    for (int L = 0; L < 5; ++L) {
        Bt[L] = (ushort*)p;
        p += align256((size_t)fo_arr[L] * Kpad_arr[L] * 2);
    }
    float* fcpart = (float*)p; p += align256((size_t)8 * MPAD * 3 * 4);
    ushort* xb   = (ushort*)p; p += align256((size_t)MPAD * 128 * 2);
    ushort* Ybuf = (ushort*)p; p += align256((size_t)MPAD * 48 * 2);
    ushort* Zbuf = (ushort*)p; p += align256((size_t)MPAD * 32 * 2);
    ushort* buf0 = (ushort*)p; p += align256((size_t)MPAD * 768 * 2);
    ushort* buf1 = (ushort*)p; p += align256((size_t)MPAD * 768 * 2);
    (void)ws_size; (void)n_in; (void)in_sizes; (void)out_size;

    // No memsets needed: deg/counts fully written by col_reduce; H/D fully
    // written by pre1's flush; csr fully written by the counting-sort scatter.

    // ---- fused pre-pass 1: LDS histograms + x->bf16 + weight conv ----
    pre1_fused<<<NB_HIST + 480 + 260, 256, 0, stream>>>(
        e_row, e_col, ew, Hpart, Dpart, x, xb,
        W[0], W[1], W[2], W[3], W[4], W[5],
        Bt1, Bt[0], Bt[1], Bt[2], Bt[3], Bt[4]);

    // ---- column reduce + per-block prefix + deg ----
    col_reduce<<<NPAD / 256, 256, 0, stream>>>(Hpart, Dpart, counts, deg);

    // ---- single-block scan: counts -> offs ----
    scan_one<<<1, 1024, 0, stream>>>(counts, offs);

    // ---- fused pre-pass 2: counting-sort scatter + L1 GEMM ----
    pre2_fused<<<NB_HIST + MPAD / 128, 256, 0, stream>>>(
        e_row, e_col, ew, deg, offs, Hpart, csr_rw, xb, Bt1, Ybuf);

    // Z = Lhat @ [Y1|Y2]  (32-wide)
    lmv_bf16<32><<<(NN + 7) / 8, 256, 0, stream>>>(
        Ybuf + 16, Zbuf, nullptr, 48, 32, offs, csr_rw, 1.0f, NN);
    // fused: z3 = Lhat@Z2 ; h1 = softplus(Y0+Z1+2z3-Y2+b1) -> buf1 [0,16), ld 64
    lmv_l1_final<<<(NN + 15) / 16, 256, 0, stream>>>(
        Zbuf, Ybuf, Bv[0], buf1, offs, csr_rw, NN);

    // ---- Layers 2..6 ----
    ushort* Abuf[5] = { buf1, buf0, buf1, buf0, buf1 };
    ushort* Obuf[5] = { buf0, buf1, buf0, buf1, buf0 };

    for (int L = 0; L < 5; ++L) {
        int fi = fi_arr[L];
        int ldA = Kpad_arr[L];
        int ldO = ldo_arr[L];
        ushort* A = Abuf[L];
        ushort* O = Obuf[L];

        // two SpMV passes: Tx1 = Lhat@Tx0; Tx2 = 2*Lhat@Tx1 - Tx0
        switch (fi) {
            case 16:
                lmv_bf16<16><<<(NN + 15) / 16, 256, 0, stream>>>(
                    A, A + fi, nullptr, ldA, ldA, offs, csr_rw, 1.0f, NN);
                lmv_bf16<16><<<(NN + 15) / 16, 256, 0, stream>>>(
                    A + fi, A + 2 * fi, A, ldA, ldA, offs, csr_rw, 2.0f, NN);
                break;
            case 32:
                lmv_bf16<32><<<(NN + 7) / 8, 256, 0, stream>>>(
                    A, A + fi, nullptr, ldA, ldA, offs, csr_rw, 1.0f, NN);
                lmv_bf16<32><<<(NN + 7) / 8, 256, 0, stream>>>(
                    A + fi, A + 2 * fi, A, ldA, ldA, offs, csr_rw, 2.0f, NN);
                break;
            case 64:    // edge-group: 4 groups x 16 lanes, ushort4/lane
                lmv_grp<16><<<NN / 4, 256, 0, stream>>>(
                    A, A + fi, nullptr, ldA, offs, csr_rw, 1.0f);
                lmv_grp<16><<<NN / 4, 256, 0, stream>>>(
                    A + fi, A + 2 * fi, A, ldA, offs, csr_rw, 2.0f);
                break;
            case 128:   // edge-group: 2 groups x 32 lanes, ushort4/lane
                lmv_grp<32><<<NN / 4, 256, 0, stream>>>(
                    A, A + fi, nullptr, ldA, offs, csr_rw, 1.0f);
                lmv_grp<32><<<NN / 4, 256, 0, stream>>>(
                    A + fi, A + 2 * fi, A, ldA, offs, csr_rw, 2.0f);
                break;
            default:  // 256
                lmv_vec<4><<<NN / 4, 256, 0, stream>>>(
                    A, A + fi, nullptr, ldA, offs, csr_rw, 1.0f);
                lmv_vec<4><<<NN / 4, 256, 0, stream>>>(
                    A + fi, A + 2 * fi, A, ldA, offs, csr_rw, 2.0f);
                break;
        }

        int K = Kpad_arr[L];
        switch (fo_arr[L]) {
            case 32:
                gemm_mfma<32><<<dim3(MPAD / 128), 256, 0, stream>>>(
                    A, ldA, K, Bt[L], Bv[L + 1], O, ldO);
                break;
            case 64:
                gemm_mfma<64><<<dim3(MPAD / 128), 256, 0, stream>>>(
                    A, ldA, K, Bt[L], Bv[L + 1], O, ldO);
                break;
            case 128:   // K=192, BK=64 DB
                gemm_bk64<false, 0><<<dim3(MPAD / 128), 256, 0, stream>>>(
                    A, ldA, K, Bt[L], Bv[L + 1], O, ldO, nullptr, nullptr);
                break;
            case 256:   // K=384, y-inner (id&1)
                gemm_bk64<false, 1><<<dim3(MPAD / 128 * 2), 256, 0, stream>>>(
                    A, ldA, K, Bt[L], Bv[L + 1], O, ldO, nullptr, nullptr);
                break;
            default:    // 512 = layer 6: K=768, fused FC -> 8 partial buffers
                gemm_bk64<true, 2><<<dim3(MPAD / 128 * 4), 256, 0, stream>>>(
                    A, ldA, K, Bt[L], Bv[L + 1], nullptr, 0, fc_w, fcpart);
                break;
        }
    }

    // ---- final: out = sum of 8 FC partials + fc_b ----
    fc_reduce<<<(NN * 3 + 255) / 256, 256, 0, stream>>>(fcpart, fc_b, out);
}